// Round 6
// baseline (554.090 us; speedup 1.0000x reference)
//
#include <hip/hip_runtime.h>
#include <math.h>

// NetNew_17162689315115: 8-layer EQL-style net, B=524288 rows.
// Reference is numpy float64; chaotic map (sin/cos at |z|~1e8-1e14) -> ENTIRE
// chain in fp64, bitwise-frozen since R3 (absmax 1245184 / thr 1646264).
// DO NOT reassociate: each z[j] = fma(W[j,k], h[k], acc) ascending k.
//
// Evidence log:
//  R4 407us (fp64 weights pre-widened to d_ws). R5/R6 allocator hints:
//  regress badly. R7 block 64 vs 256: neutral. R8 j-blocking: neutral
//  (unified file ~224 regs -> 2 waves/SIMD).
//  R9 I$ shrink (rolled j-loop + shared noinline transcendentals):
//  407 -> 222us. Straight-line code streams I$ with ~zero reuse.
//  R10 merged transcendental calls: ~neutral.
//  R11 inline exp/log, shared noinline sincos, j-unroll 2: 222 -> 214us
//  (VALUBusy 56%, occ 22.7% == 2 waves/SIMD, HBM 0.6%). BEST so far.
//  R12 LDS h-split + launch_bounds(64,3): 604us — scratch spill disaster.
//  Occupancy-increase axis CLOSED (live set needs ~118 dbl/thread).
//  R13 j-unroll 4: 244us (I$ streaming: code grew at fixed work).
//  R14 W->LDS 64-thr: 369us (LDS capped occ at 1 wave/SIMD) BUT per-wave
//  issue efficiency rose 28%->34% -> ~38us of R11's stall is weight-fetch.
//  R15 W->LDS 256-thr (iso-occupancy): 261us — ds_read path adds instrs +
//  lgkmcnt deps, loses free SGPR fma operands. LDS weight storage CLOSED.
//  R16 512-blk + per-layer __syncthreads (K$ phase-align): 252us — barrier
//  waits on sincos duration variance swamp any K$ gain. CLOSED.
//  Invariant: busy-time ~120us in every variant; only stall moves.
// R17: TWO ROWS PER THREAD at 1 wave/SIMD (launch_bounds(64,1) releases the
// full 512-reg file). One s_load of W feeds BOTH rows' fmas -> scalar
// weight stream per unit work HALVES (attacks the ~38us fetch-stall term);
// 4 independent fma chains (2 rows x unroll 2) interleave at instruction
// granularity (attacks the dep-chain term). Code per ROW stays at R11 level
// (code doubles, work doubles — I$-streaming cost per row unchanged, unlike
// R13). Worst live set ~390 regs < 512. Bitwise-neutral: each row runs
// exactly R11's op sequence. TRIPWIRE: WRITE_SIZE must stay 2048KB; if it
// balloons the allocator spilled -> revert to R11.

static constexpr double MAX_MLT   = 99999999.0;
static constexpr double MAX_DIV   = 9999.0;
static constexpr double MAX_EXP_C = 17.0;
static constexpr double MIN_DENOM = 0.0001;

static constexpr int IN0  = 8;   // vari_num + const_num
static constexpr int VDIM = 13;  // rows of each W
static constexpr int NOPS = 9;   // ops appended per layer
static constexpr int FDIM = 80;  // final h dim: 8 + 8*9

// layer weight element counts and fp64 workspace offsets
// in_dims: 8,17,26,35,44,53,62,71 ; W_i is 13 x in_dim ; Wf is 1 x 80
static constexpr int WSZ[9]  = {104, 221, 338, 455, 572, 689, 806, 923, 80};
static constexpr int WOFF[9] = {0, 104, 325, 663, 1118, 1690, 2379, 3185, 4108};

// ---- prep: widen fp32 weights -> fp64 workspace (exact, bitwise-neutral) ----
__global__ void widen_kernel(const float* __restrict__ s0, const float* __restrict__ s1,
                             const float* __restrict__ s2, const float* __restrict__ s3,
                             const float* __restrict__ s4, const float* __restrict__ s5,
                             const float* __restrict__ s6, const float* __restrict__ s7,
                             const float* __restrict__ s8, double* __restrict__ dst) {
    int seg = blockIdx.y;
    int i   = blockIdx.x * blockDim.x + threadIdx.x;
    const float* src;
    switch (seg) {
        case 0: src = s0; break; case 1: src = s1; break; case 2: src = s2; break;
        case 3: src = s3; break; case 4: src = s4; break; case 5: src = s5; break;
        case 6: src = s6; break; case 7: src = s7; break; default: src = s8; break;
    }
    if (i < WSZ[seg]) dst[WOFF[seg] + i] = (double)src[i];
}

// ---- one shared body for the two PH-heavy (branchy) functions ----
struct D2 { double s, c; };
__device__ __attribute__((noinline))
D2 d_sincos2(double as, double ac) {
    D2 r;
    r.s = sin(as);
    r.c = cos(ac);
    return r;
}

// _clip_mag forward, float64: scale = |mx/v|, o = where(|v|>=mx, v*scale, v).
// NaN passes through (compare false), matching jnp.where.
__device__ __forceinline__ double clip_ref(double v, double mx) {
    double scale = fabs(mx / v);
    double vs    = v * scale;
    return (fabs(v) >= mx) ? vs : v;
}

// Ops section for one row (identical sequence to R11 -> bitwise-neutral).
template<int BO>
__device__ __forceinline__ void ops_row(const double (&z)[VDIM], double (&h)[FDIM]) {
    h[BO + 0] = z[0] + z[1];
    h[BO + 1] = z[2] - z[3];
    h[BO + 2] = clip_ref(z[4] * z[5], MAX_MLT);
    {
        double b     = z[7];
        double denom = (b == 0.0) ? (b + MIN_DENOM) : b;
        h[BO + 3]    = clip_ref(z[6] / denom, MAX_DIV);
    }
    {
        D2 t = d_sincos2(z[8], z[9]);   // shared noinline: PH-heavy bodies
        h[BO + 4] = t.s;
        h[BO + 5] = t.c;
    }
    {
        double a    = z[10];
        double safe = (a >= MAX_EXP_C) ? (a * (MAX_EXP_C / a)) : a;
        h[BO + 6]   = exp(safe);        // inlined: branch-light, schedules in
    }
    h[BO + 7] = log(fabs(z[11]));       // inlined: branch-light
    h[BO + 8] = clip_ref(z[12] * z[12], MAX_MLT);
}

template<int IN_DIM, int BASE>
__device__ __forceinline__ void layer_step2(const double* __restrict__ W,
                                            double (&hA)[FDIM], double (&hB)[FDIM]) {
    double zA[VDIM], zB[VDIM];
    // Rolled j-loop, unroll 2: 2 j-rows x 2 data-rows = 4 independent fma
    // chains in flight, sharing each W s_load. Each chain is the same
    // ascending-k fma sequence as R11 -> bitwise equal per row.
    #pragma unroll 2
    for (int j = 0; j < VDIM; ++j) {
        const double* Wr = W + j * IN_DIM;
        double aA = 0.0, aB = 0.0;
        #pragma unroll
        for (int k = 0; k < IN_DIM; ++k) {
            double w = Wr[k];                     // ONE scalar load, TWO uses
            aA = fma(w, hA[BASE + k], aA);        // frozen accum order
            aB = fma(w, hB[BASE + k], aB);
        }
        zA[j] = aA;
        zB[j] = aB;
    }
    constexpr int BO = BASE - NOPS;
    ops_row<BO>(zA, hA);
    ops_row<BO>(zB, hB);
}

__global__ void __launch_bounds__(64, 1)
net_kernel(const float* __restrict__ x, const double* __restrict__ Wd,
           float* __restrict__ out, int nrows) {
    int half = nrows >> 1;                       // nrows = 524288, even
    int tid  = blockIdx.x * blockDim.x + threadIdx.x;
    bool active = tid < half;
    int rA = active ? tid : 0;
    int rB = rA + half;                          // both groups coalesced

    double hA[FDIM], hB[FDIM];

    // x occupies the TAIL of the final feature vector (each layer prepends).
    const float4* x4 = reinterpret_cast<const float4*>(x);
    {
        float4 a0 = x4[rA * 2 + 0], a1 = x4[rA * 2 + 1];
        hA[72] = (double)a0.x; hA[73] = (double)a0.y; hA[74] = (double)a0.z; hA[75] = (double)a0.w;
        hA[76] = (double)a1.x; hA[77] = (double)a1.y; hA[78] = (double)a1.z; hA[79] = (double)a1.w;
        float4 b0 = x4[rB * 2 + 0], b1 = x4[rB * 2 + 1];
        hB[72] = (double)b0.x; hB[73] = (double)b0.y; hB[74] = (double)b0.z; hB[75] = (double)b0.w;
        hB[76] = (double)b1.x; hB[77] = (double)b1.y; hB[78] = (double)b1.z; hB[79] = (double)b1.w;
    }

    layer_step2<IN0 + 0 * NOPS, 72>(Wd + WOFF[0], hA, hB);  // in  8, out@63
    layer_step2<IN0 + 1 * NOPS, 63>(Wd + WOFF[1], hA, hB);  // in 17, out@54
    layer_step2<IN0 + 2 * NOPS, 54>(Wd + WOFF[2], hA, hB);  // in 26, out@45
    layer_step2<IN0 + 3 * NOPS, 45>(Wd + WOFF[3], hA, hB);  // in 35, out@36
    layer_step2<IN0 + 4 * NOPS, 36>(Wd + WOFF[4], hA, hB);  // in 44, out@27
    layer_step2<IN0 + 5 * NOPS, 27>(Wd + WOFF[5], hA, hB);  // in 53, out@18
    layer_step2<IN0 + 6 * NOPS, 18>(Wd + WOFF[6], hA, hB);  // in 62, out@9
    layer_step2<IN0 + 7 * NOPS,  9>(Wd + WOFF[7], hA, hB);  // in 71, out@0

    // Final dots stay unrolled: h indices must remain static. One Wf load
    // feeds both rows. Same ascending-k fma chain per row.
    const double* Wf = Wd + WOFF[8];
    double accA = 0.0, accB = 0.0;
    #pragma unroll
    for (int k = 0; k < FDIM; ++k) {
        double w = Wf[k];
        accA = fma(w, hA[k], accA);
        accB = fma(w, hB[k], accB);
    }
    if (active) {
        out[rA] = (float)accA;
        out[rB] = (float)accB;
    }
}

extern "C" void kernel_launch(void* const* d_in, const int* in_sizes, int n_in,
                              void* d_out, int out_size, void* d_ws, size_t ws_size,
                              hipStream_t stream) {
    const float* x = (const float*)d_in[0];
    double* Wd     = (double*)d_ws;   // 4188 doubles = 33.5 KB
    float* out     = (float*)d_out;

    // widen weights (d_ws is re-poisoned before every call -> must rewrite)
    {
        dim3 grid((923 + 255) / 256, 9);
        widen_kernel<<<grid, 256, 0, stream>>>(
            (const float*)d_in[1], (const float*)d_in[2], (const float*)d_in[3],
            (const float*)d_in[4], (const float*)d_in[5], (const float*)d_in[6],
            (const float*)d_in[7], (const float*)d_in[8], (const float*)d_in[9],
            Wd);
    }

    int nrows = in_sizes[0] / IN0;   // 524288
    int half  = nrows / 2;
    int block = 64;
    int grid  = (half + block - 1) / block;
    net_kernel<<<grid, block, 0, stream>>>(x, Wd, out, nrows);
}

// Round 7
// 277.041 us; speedup vs baseline: 2.0000x; 2.0000x over previous
//
#include <hip/hip_runtime.h>
#include <math.h>

// NetNew_17162689315115: 8-layer EQL-style net, B=524288 rows.
// Reference is numpy float64; chaotic map (sin/cos at |z|~1e8-1e14) -> ENTIRE
// chain in fp64, bitwise-frozen since R3 (absmax 1245184 / thr 1646264).
// DO NOT reassociate: each z[j] = fma(W[j,k], h[k], acc) ascending k.
//
// Evidence log:
//  R4 407us (fp64 weights pre-widened to d_ws). R5/R6 allocator hints:
//  regress badly. R7 block 64 vs 256: neutral (measured on pre-I$-fix code;
//  K$ effects invisible there). R8 j-blocking: neutral (~224 unified regs
//  -> 2 waves/SIMD cap).
//  R9 I$ shrink (rolled j-loop + shared noinline transcendentals):
//  407 -> 222us. Straight-line code streams I$ with ~zero reuse.
//  R10 merged transcendental calls: ~neutral.
//  R11 inline exp/log, shared noinline sincos, j-unroll 2: 222 -> 214us
//  (VALUBusy 56%, occ 22.7% == 2 waves/SIMD, HBM 0.6%). BEST.
//  R12 LDS h-split + launch_bounds(64,3): 604us — scratch spill. Occupancy-
//  increase axis CLOSED (live set ~118 dbl/thread can't fit 3-wave corridor).
//  R13 j-unroll 4: 244us (I$ streaming; also proves matmul chains already
//  issue-saturated at 2 waves — more chains don't help).
//  R14 W->LDS 64-thr: 369us (LDS capped occ) BUT per-wave issue efficiency
//  28%->34% with local weights -> weight-fetch stall is real (~25Kcyc/pass).
//  R15 W->LDS 256-thr (iso-occupancy): 261us — 8 waves/CU saturate the DS
//  pipe (2094 ds_read/pass/wave); also loses free SGPR fma operands. CLOSED.
//  R16 512-blk + per-layer __syncthreads: 252us — barrier converts sincos
//  duration variance into everyone-waits. Barrier alignment CLOSED.
//  R17 2 rows/thread @ 1 wave: 490us — live set crosses the 256-VGPR
//  addressability wall; AGPR moves + scratch (WRITE 10MB) + busy +42us.
//  Per-thread state hard-capped ~112 doubles. Multi-row ILP CLOSED.
//  Invariant: busy ~120us in EVERY variant; only the ~93us stall moves.
//  Stall arithmetic: ~524 sK$ line misses/pass x ~50cyc exposed ~= 26Kcyc
//  ~= measured 28Kcyc/pass idle. K$ thrash = 8 blocks/CU streaming 33.5KB
//  at 8 drifting offsets through a ~16KB scalar cache.
// R18: R11's EXACT code, block = 512 (8 waves = full CU residency in ONE
// block, NO barriers). One weight stream per CU instead of 8; waves start
// together and drift slowly -> per-CU scalar working set ~= 1-2 layers
// (<=14KB, fits K$). First wave misses, 7 hit. Zero instruction change;
// registers/occupancy unchanged (224 x 8 waves fits). Bitwise-neutral.

static constexpr double MAX_MLT   = 99999999.0;
static constexpr double MAX_DIV   = 9999.0;
static constexpr double MAX_EXP_C = 17.0;
static constexpr double MIN_DENOM = 0.0001;

static constexpr int IN0  = 8;   // vari_num + const_num
static constexpr int VDIM = 13;  // rows of each W
static constexpr int NOPS = 9;   // ops appended per layer
static constexpr int FDIM = 80;  // final h dim: 8 + 8*9
static constexpr int BDIM = 512; // 8 waves = full CU residency, one K$ stream

// layer weight element counts and fp64 workspace offsets
// in_dims: 8,17,26,35,44,53,62,71 ; W_i is 13 x in_dim ; Wf is 1 x 80
static constexpr int WSZ[9]  = {104, 221, 338, 455, 572, 689, 806, 923, 80};
static constexpr int WOFF[9] = {0, 104, 325, 663, 1118, 1690, 2379, 3185, 4108};

// ---- prep: widen fp32 weights -> fp64 workspace (exact, bitwise-neutral) ----
__global__ void widen_kernel(const float* __restrict__ s0, const float* __restrict__ s1,
                             const float* __restrict__ s2, const float* __restrict__ s3,
                             const float* __restrict__ s4, const float* __restrict__ s5,
                             const float* __restrict__ s6, const float* __restrict__ s7,
                             const float* __restrict__ s8, double* __restrict__ dst) {
    int seg = blockIdx.y;
    int i   = blockIdx.x * blockDim.x + threadIdx.x;
    const float* src;
    switch (seg) {
        case 0: src = s0; break; case 1: src = s1; break; case 2: src = s2; break;
        case 3: src = s3; break; case 4: src = s4; break; case 5: src = s5; break;
        case 6: src = s6; break; case 7: src = s7; break; default: src = s8; break;
    }
    if (i < WSZ[seg]) dst[WOFF[seg] + i] = (double)src[i];
}

// ---- one shared body for the two PH-heavy (branchy) functions ----
struct D2 { double s, c; };
__device__ __attribute__((noinline))
D2 d_sincos2(double as, double ac) {
    D2 r;
    r.s = sin(as);
    r.c = cos(ac);
    return r;
}

// _clip_mag forward, float64: scale = |mx/v|, o = where(|v|>=mx, v*scale, v).
// NaN passes through (compare false), matching jnp.where.
__device__ __forceinline__ double clip_ref(double v, double mx) {
    double scale = fabs(mx / v);
    double vs    = v * scale;
    return (fabs(v) >= mx) ? vs : v;
}

template<int IN_DIM, int BASE>
__device__ __forceinline__ void layer_step(const double* __restrict__ W,
                                           double (&h)[FDIM]) {
    double z[VDIM];
    // Rolled j-loop, unroll 2 (R13: more chains regress via I$ streaming;
    // matmul is already issue-saturated at 2 waves). Each z[j] is the same
    // ascending-k fma chain as the fully-unrolled form -> bitwise equal.
    // k stays unrolled so every h index is compile-time constant. W is
    // wave-uniform -> s_load path, weights feed v_fma_f64 as SGPR operands.
    #pragma unroll 2
    for (int j = 0; j < VDIM; ++j) {
        const double* Wr = W + j * IN_DIM;
        double acc = 0.0;
        #pragma unroll
        for (int k = 0; k < IN_DIM; ++k) {
            acc = fma(Wr[k], h[BASE + k], acc);  // frozen accum order
        }
        z[j] = acc;
    }
    constexpr int BO = BASE - NOPS;
    // op order: + - * / sin cos exp log square, consuming z cols in order
    h[BO + 0] = z[0] + z[1];
    h[BO + 1] = z[2] - z[3];
    h[BO + 2] = clip_ref(z[4] * z[5], MAX_MLT);
    {
        double b     = z[7];
        double denom = (b == 0.0) ? (b + MIN_DENOM) : b;
        h[BO + 3]    = clip_ref(z[6] / denom, MAX_DIV);
    }
    {
        D2 t = d_sincos2(z[8], z[9]);   // shared noinline: PH-heavy bodies
        h[BO + 4] = t.s;
        h[BO + 5] = t.c;
    }
    {
        double a    = z[10];
        double safe = (a >= MAX_EXP_C) ? (a * (MAX_EXP_C / a)) : a;
        h[BO + 6]   = exp(safe);        // inlined: branch-light, schedules in
    }
    h[BO + 7] = log(fabs(z[11]));       // inlined: branch-light
    h[BO + 8] = clip_ref(z[12] * z[12], MAX_MLT);
}

__global__ void __launch_bounds__(BDIM)
net_kernel(const float* __restrict__ x, const double* __restrict__ Wd,
           float* __restrict__ out, int nrows) {
    int row = blockIdx.x * blockDim.x + threadIdx.x;
    if (row >= nrows) return;   // B = 524288 = 1024*512 -> no tail

    double h[FDIM];

    // x occupies the TAIL of the final feature vector (each layer prepends).
    const float4* x4 = reinterpret_cast<const float4*>(x);
    float4 xa = x4[row * 2 + 0];
    float4 xb = x4[row * 2 + 1];
    h[72] = (double)xa.x; h[73] = (double)xa.y; h[74] = (double)xa.z; h[75] = (double)xa.w;
    h[76] = (double)xb.x; h[77] = (double)xb.y; h[78] = (double)xb.z; h[79] = (double)xb.w;

    layer_step<IN0 + 0 * NOPS, 72>(Wd + WOFF[0], h);  // in_dim  8, write at 63
    layer_step<IN0 + 1 * NOPS, 63>(Wd + WOFF[1], h);  // in_dim 17, write at 54
    layer_step<IN0 + 2 * NOPS, 54>(Wd + WOFF[2], h);  // in_dim 26, write at 45
    layer_step<IN0 + 3 * NOPS, 45>(Wd + WOFF[3], h);  // in_dim 35, write at 36
    layer_step<IN0 + 4 * NOPS, 36>(Wd + WOFF[4], h);  // in_dim 44, write at 27
    layer_step<IN0 + 5 * NOPS, 27>(Wd + WOFF[5], h);  // in_dim 53, write at 18
    layer_step<IN0 + 6 * NOPS, 18>(Wd + WOFF[6], h);  // in_dim 62, write at  9
    layer_step<IN0 + 7 * NOPS,  9>(Wd + WOFF[7], h);  // in_dim 71, write at  0

    // Final dot stays unrolled: h indices must remain static (any dynamic h
    // access would force the whole array to scratch).
    const double* Wf = Wd + WOFF[8];
    double acc = 0.0;
    #pragma unroll
    for (int k = 0; k < FDIM; ++k) {
        acc = fma(Wf[k], h[k], acc);
    }
    out[row] = (float)acc;
}

extern "C" void kernel_launch(void* const* d_in, const int* in_sizes, int n_in,
                              void* d_out, int out_size, void* d_ws, size_t ws_size,
                              hipStream_t stream) {
    const float* x = (const float*)d_in[0];
    double* Wd     = (double*)d_ws;   // 4188 doubles = 33.5 KB
    float* out     = (float*)d_out;

    // widen weights (d_ws is re-poisoned before every call -> must rewrite)
    {
        dim3 grid((923 + 255) / 256, 9);
        widen_kernel<<<grid, 256, 0, stream>>>(
            (const float*)d_in[1], (const float*)d_in[2], (const float*)d_in[3],
            (const float*)d_in[4], (const float*)d_in[5], (const float*)d_in[6],
            (const float*)d_in[7], (const float*)d_in[8], (const float*)d_in[9],
            Wd);
    }

    int nrows = in_sizes[0] / IN0;
    int block = BDIM;
    int grid  = (nrows + block - 1) / block;
    net_kernel<<<grid, block, 0, stream>>>(x, Wd, out, nrows);
}